// Round 6
// baseline (2991.120 us; speedup 1.0000x reference)
//
#include <hip/hip_runtime.h>

typedef unsigned short u16;
typedef unsigned long long u64;
typedef __attribute__((ext_vector_type(8))) short bfrag;
typedef __attribute__((ext_vector_type(4))) float f32x4;

#define MFMA __builtin_amdgcn_mfma_f32_16x16x32_bf16

// ---------------- ws layout (bytes) ----------------
#define OFF_FLAGS 0ull           //  4096: flags[8 groups][2 halves][64 ints]
#define OFF_HENC  4096ull        //  524288 ([2][512][256] bf16)  <- memset w/ flags
#define OFF_WENC  528384ull      //  589824
#define OFF_WDEC  1118208ull     //  2752512
#define OFF_WY    3870720ull     //  131072
#define OFF_WMS   4001792ull     //  278528 ([256][544] bf16)
#define OFF_WH0   4280320ull     //  163840 ([512][160] bf16)
#define OFF_HDEC  4444160ull     //  1048576 ([2][512][512] bf16)
#define OFF_HLAT  5492736ull     //  557056 ([512][544] bf16)
#define OFF_AZ    6049792ull     //  163840 ([512][160] bf16)
#define OFF_SX    6213632ull     //  2097152 ([256][512][8] bf16)

__device__ __forceinline__ u16 f2bf(float f) {
  union { float f; unsigned int i; } v; v.f = f;
  unsigned int r = v.i + 0x7fffu + ((v.i >> 16) & 1u);
  return (u16)(r >> 16);
}
__device__ __forceinline__ float sigm(float x) { return 1.0f / (1.0f + __expf(-x)); }
__device__ __forceinline__ float tanh_(float x) {
  float a = fabsf(x);
  float e = __expf(-2.0f * a);
  float r = (1.0f - e) / (1.0f + e);
  return x < 0.0f ? -r : r;
}

// relaxed agent-scope data movers: MALL-coherent, NO wbl2/inv fences (r4-proven)
__device__ __forceinline__ u64 aload(const u64* p) {
  return __hip_atomic_load(p, __ATOMIC_RELAXED, __HIP_MEMORY_SCOPE_AGENT);
}
__device__ __forceinline__ void astore(u64* p, u64 v) {
  __hip_atomic_store(p, v, __ATOMIC_RELAXED, __HIP_MEMORY_SCOPE_AGENT);
}
__device__ __forceinline__ float afload(const float* p) {
  return __hip_atomic_load(p, __ATOMIC_RELAXED, __HIP_MEMORY_SCOPE_AGENT);
}
__device__ __forceinline__ void afstore(float* p, float v) {
  __hip_atomic_store(p, v, __ATOMIC_RELAXED, __HIP_MEMORY_SCOPE_AGENT);
}

// half-group barrier: 32 blocks; one wave polls 32 flags. base = per-(group,half) slot.
__device__ __forceinline__ void gwait(int* base, int ep, int tid, int* sdead) {
  if (ep > 0) {
    if (tid < 32 && *sdead == 0) {
      int* fp = base + tid;
      int spin = 0;
      while (__hip_atomic_load(fp, __ATOMIC_RELAXED, __HIP_MEMORY_SCOPE_AGENT) < ep) {
        __builtin_amdgcn_s_sleep(1);
        if (++spin > (1 << 18)) { *sdead = 1; break; }   // fail loud, never hang
      }
    }
  }
  __syncthreads();
  asm volatile("" ::: "memory");
}
__device__ __forceinline__ void garrive(int* base, int m, int ep, int tid) {
  asm volatile("s_waitcnt vmcnt(0)" ::: "memory");  // data stores ack'd at MALL
  __syncthreads();
  if (tid == 0)
    __hip_atomic_store(base + m, ep, __ATOMIC_RELAXED, __HIP_MEMORY_SCOPE_AGENT);
}

// ============================================================= prep packs
__global__ void pack_wenc(const float* __restrict__ Whh, const float* __restrict__ Wih,
                          const float* __restrict__ bi, const float* __restrict__ bh,
                          u16* __restrict__ out) {
  int idx = blockIdx.x * 256 + threadIdx.x;
  if (idx >= 294912) return;
  int m = idx / 9216, within = idx % 9216;
  int kb = within >> 10, rest = within & 1023;
  int ng = rest >> 9, l = (rest >> 3) & 63, j = rest & 7;
  int nl = ng * 16 + (l & 15);
  int u = nl >> 2, g = nl & 3;
  int row = g * 256 + m * 8 + u;
  int k = kb * 32 + (l >> 4) * 8 + j;
  float v = 0.f;
  if (k < 256) v = Whh[row * 256 + k];
  else if (k < 261) v = Wih[row * 5 + (k - 256)];
  else if (k == 261) v = bi[row] + bh[row];
  out[idx] = f2bf(v);
}

__global__ void pack_wdec(const float* __restrict__ Whh, const float* __restrict__ Wih,
                          const float* __restrict__ bi, const float* __restrict__ bh,
                          u16* __restrict__ out) {
  int idx = blockIdx.x * 256 + threadIdx.x;
  if (idx >= 1376256) return;
  int m = idx / 43008, within = idx % 43008;
  int kb = within >> 11, rest = within & 2047;
  int w = rest >> 9, l = (rest >> 3) & 63, j = rest & 7;
  int nl = w * 16 + (l & 15);
  int u = nl >> 2, g = nl & 3;
  int row = g * 512 + m * 16 + u;
  int k = kb * 32 + (l >> 4) * 8 + j;
  float v = 0.f;
  if (k < 512) v = Whh[row * 512 + k];                    // h
  else if (k < 640) v = Wih[row * 133 + 5 + (k - 512)];   // z
  else if (k < 645) v = Wih[row * 133 + (k - 640)];       // x
  else if (k == 645) v = bi[row] + bh[row];
  out[idx] = f2bf(v);
}

__global__ void pack_wy(const float* __restrict__ Wd, u16* __restrict__ out) {
  int idx = blockIdx.x * 256 + threadIdx.x;
  if (idx >= 65536) return;
  int m = idx >> 13, within = idx & 8191;
  int kb = within >> 9, rest = within & 511;
  int l = rest >> 3, j = rest & 7;
  int row = m * 16 + (l & 15);
  int k = kb * 32 + (l >> 4) * 8 + j;
  float v = (row < 123 && k < 512) ? Wd[row * 512 + k] : 0.f;
  out[idx] = f2bf(v);
}

__global__ void pack_wms(const float* __restrict__ Wmu, const float* __restrict__ bmu,
                         const float* __restrict__ Wsig, const float* __restrict__ bsig,
                         u16* __restrict__ out) {
  int idx = blockIdx.x * 256 + threadIdx.x;
  if (idx >= 139264) return;
  int r = idx / 544, k = idx % 544;
  float v = 0.f;
  if (r < 128) {
    if (k < 512) v = Wmu[r * 512 + k];
    else if (k == 512) v = bmu[r];
  } else {
    int r2 = r - 128;
    if (k < 512) v = Wsig[r2 * 512 + k];
    else if (k == 512) v = bsig[r2];
  }
  out[idx] = f2bf(v);
}

__global__ void pack_wh0(const float* __restrict__ Wh0, const float* __restrict__ bh0,
                         u16* __restrict__ out) {
  int idx = blockIdx.x * 256 + threadIdx.x;
  if (idx >= 81920) return;
  int r = idx / 160, k = idx % 160;
  float v = 0.f;
  if (k < 128) v = Wh0[r * 128 + k];
  else if (k == 128) v = bh0[r];
  out[idx] = f2bf(v);
}

// s -> bf16 [t][b][8]: cols 0..4 = x, col 5 = 1.0 (bias), 6..7 = 0
__global__ void pack_sx(const float* __restrict__ s, u16* __restrict__ out) {
  int idx = blockIdx.x * 256 + threadIdx.x;
  if (idx >= 1048576) return;
  int j = idx & 7, b = (idx >> 3) & 511, t = idx >> 12;
  u16 v;
  if (j < 5) v = f2bf(s[((size_t)b * 256 + t) * 5 + j]);
  else v = (j == 5) ? (u16)0x3F80 : (u16)0;
  out[idx] = v;
}

// ============================================================= persistent
// group g = blk & 7, member m = blk >> 3. Group owns batch [g*64, g*64+64).
// Per-half flag sets: FA (rows +0..31), FB (rows +32..63) — independent chains.
__global__ __launch_bounds__(256, 1) void rnn_persist(
    int* __restrict__ flags, u16* __restrict__ henc,
    const u16* __restrict__ WENCP, const u16* __restrict__ WDECP,
    const u16* __restrict__ WYP, const u16* __restrict__ WMSP, const u16* __restrict__ WH0P,
    u16* __restrict__ hdec, u16* __restrict__ hlat, u16* __restrict__ Az,
    const u16* __restrict__ SXD,
    const float* __restrict__ s, const float* __restrict__ eps,
    const float* __restrict__ Wih_b, const float* __restrict__ bih_b,
    const float* __restrict__ bhh_b,
    const float* __restrict__ b_dec, float* __restrict__ out)
{
  // LDS: A-tile [32][680] u16 (43520B) | gate W (86016B) | y W (16384B)
  __shared__ __align__(16) u16 sm[72960];
  __shared__ __align__(16) float gbuf[2112];   // [32][66] f32 (latent scratch aliases)
  __shared__ __align__(16) u16 hst[1024];
  __shared__ int sdead;

  const int tid = threadIdx.x;
  const int blk = blockIdx.x;
  const int g = blk & 7;
  const int m = blk >> 3;
  const int B0 = g * 64;
  const int w = tid >> 6, l = tid & 63;
  const int lr = l & 15, ko = (l >> 4) * 8;
  int* FA = flags + g * 128;
  int* FB = FA + 64;

  float* out_mu = out + 16121856;
  float* out_ps = out + 16187392;

  const int gcol = m * 16 + lr;
  float bd = 0.f;
  if (m < 8 && gcol < 123) bd = b_dec[gcol];

  if (tid == 0) sdead = 0;
  // zero encoder A region (pads stay zero)
  {
    bfrag zz = {0, 0, 0, 0, 0, 0, 0, 0};
    #pragma unroll
    for (int i = 0; i < 5; ++i) {
      int c = i * 256 + tid;
      if (c < 1184) *(bfrag*)(sm + c * 8) = zz;   // 32*296 u16
    }
  }
  // encoder weight slice -> LDS
  {
    const u16* src = WENCP + (size_t)m * 9216;
    #pragma unroll
    for (int i = 0; i < 5; ++i) {
      int c = i * 256 + tid;
      if (c < 1152) *(bfrag*)(sm + 21760 + c * 8) = *(const bfrag*)(src + c * 8);
    }
  }
  __syncthreads();

  // ---------------- encoder: 256 steps x 2 independent half-chains ----------------
  float c_enc0 = 0.f, c_enc1 = 0.f;
  #pragma unroll 1
  for (int t = 0; t < 256; ++t) {
    #pragma unroll
    for (int X = 0; X < 2; ++X) {
      int* F = X ? FB : FA;
      gwait(F, t, tid, &sdead);
      const u64* hs = (const u64*)(henc + (size_t)((t + 1) & 1) * 131072 +
                                   (size_t)(B0 + X * 32) * 256);
      u64 hv[8];
      #pragma unroll
      for (int i = 0; i < 8; ++i) hv[i] = aload(hs + i * 256 + tid);
      #pragma unroll
      for (int i = 0; i < 8; ++i) {
        int idx = i * 256 + tid;
        *(u64*)(sm + (idx >> 6) * 296 + (idx & 63) * 4) = hv[i];
      }
      if (tid < 64) {   // x|bias cols 256..263 from packed SX
        int row = tid >> 1, q = tid & 1;
        *(u64*)(sm + row * 296 + 256 + q * 4) =
            *(const u64*)(SXD + ((size_t)(t * 512 + B0 + X * 32 + row)) * 8 + q * 4);
      }
      __syncthreads();
      const int mt = w >> 1, ng = w & 1;
      f32x4 acc = {0.f, 0.f, 0.f, 0.f};
      #pragma unroll
      for (int kb = 0; kb < 9; ++kb) {
        bfrag a = *(const bfrag*)(sm + (mt * 16 + lr) * 296 + kb * 32 + ko);
        bfrag bw = *(const bfrag*)(sm + 21760 + (kb * 2 + ng) * 512 + l * 8);
        acc = MFMA(a, bw, acc, 0, 0, 0);
      }
      #pragma unroll
      for (int j = 0; j < 4; ++j)
        gbuf[(mt * 16 + (l >> 4) * 4 + j) * 33 + ng * 16 + lr] = acc[j];
      __syncthreads();
      {
        int bl = tid >> 3, u = tid & 7;
        float gi = gbuf[bl * 33 + u * 4 + 0], gf = gbuf[bl * 33 + u * 4 + 1];
        float gg = gbuf[bl * 33 + u * 4 + 2], go = gbuf[bl * 33 + u * 4 + 3];
        float cprev = (X == 0) ? c_enc0 : c_enc1;
        float c = sigm(gf) * cprev + sigm(gi) * tanh_(gg);
        if (X == 0) c_enc0 = c; else c_enc1 = c;
        hst[bl * 8 + u] = f2bf(sigm(go) * tanh_(c));
      }
      __syncthreads();
      if (tid < 64) {
        int row = tid >> 1, q = tid & 1;
        u64 v = *(const u64*)(hst + row * 8 + q * 4);
        astore((u64*)(henc + (size_t)(t & 1) * 131072 +
                      (size_t)(B0 + X * 32 + row) * 256 + m * 8) + q, v);
      }
      garrive(F, m, t + 1, tid);
    }
  }

  // ---------------- latent (epochs on FA; FB bumped at end) ----------------
  u16* lat_hf = (u16*)gbuf;          // [2][256]
  u16* lat_hb = (u16*)gbuf + 512;    // [2][256]
  u16* lat_z  = (u16*)gbuf + 1024;   // [2][128]

  gwait(FA, 256, tid, &sdead);
  gwait(FB, 256, tid, &sdead);
  {  // decoder gate weights -> LDS (overlaps latent math)
    const u16* src = WDECP + (size_t)m * 43008;
    #pragma unroll 1
    for (int i = 0; i < 21; ++i) {
      int c = i * 256 + tid;
      *(bfrag*)(sm + 21760 + c * 8) = *(const bfrag*)(src + c * 8);
    }
  }
  if (m < 8) {
    const u16* src = WYP + (size_t)m * 8192;
    #pragma unroll
    for (int i = 0; i < 4; ++i) {
      int c = i * 256 + tid;
      *(bfrag*)(sm + 64768 + c * 8) = *(const bfrag*)(src + c * 8);
    }
  }
  // Lphase A: backward-LSTM 1 step + hlat rows
  #pragma unroll
  for (int r = 0; r < 2; ++r) {
    int b = B0 + m * 2 + r;
    if (tid < 64) {
      u64 v = aload((const u64*)(henc + 131072 + (size_t)b * 256) + tid);
      *(u64*)(lat_hf + r * 256 + tid * 4) = v;
    }
    {
      const float* xr = s + ((size_t)b * 256 + 255) * 5;
      float x0 = xr[0], x1 = xr[1], x2 = xr[2], x3 = xr[3], x4 = xr[4];
      int n = tid;
      float gv[4];
      #pragma unroll
      for (int gg = 0; gg < 4; ++gg) {
        int row = gg * 256 + n;
        gv[gg] = bih_b[row] + bhh_b[row] + x0 * Wih_b[row * 5] + x1 * Wih_b[row * 5 + 1] +
                 x2 * Wih_b[row * 5 + 2] + x3 * Wih_b[row * 5 + 3] + x4 * Wih_b[row * 5 + 4];
      }
      float c = sigm(gv[0]) * tanh_(gv[2]);
      lat_hb[r * 256 + n] = f2bf(sigm(gv[3]) * tanh_(c));
    }
  }
  __syncthreads();
  #pragma unroll
  for (int it = 0; it < 2; ++it) {
    int idx = it * 256 + tid;
    if (idx < 272) {
      int rr = idx / 136, u = idx % 136;
      u64 pv = 0;
      #pragma unroll
      for (int q = 0; q < 4; ++q) {
        int c = u * 4 + q;
        u16 x;
        if (c < 256) x = lat_hf[rr * 256 + c];
        else if (c < 512) x = lat_hb[rr * 256 + c - 256];
        else if (c == 512) x = 0x3F80;
        else x = 0;
        pv |= ((u64)x) << (q * 16);
      }
      astore((u64*)(hlat + (size_t)(B0 + m * 2 + rr) * 544) + u, pv);
    }
  }
  garrive(FA, m, 257, tid);

  // Lphase B: [mu|presig] = hlat @ WMS^T -> d_out directly
  gwait(FA, 257, tid, &sdead);
  {
    const int bH = m >> 4, cT = m & 15;
    const u64* src = (const u64*)(hlat + (size_t)(B0 + bH * 32) * 544);
    u64 sv[17];
    #pragma unroll
    for (int i = 0; i < 17; ++i) sv[i] = aload(src + i * 256 + tid);
    #pragma unroll
    for (int i = 0; i < 17; ++i) *(u64*)(sm + (i * 256 + tid) * 4) = sv[i];
    __syncthreads();
    if (w < 2) {
      f32x4 acc = {0.f, 0.f, 0.f, 0.f};
      const u16* bp = WMSP + (size_t)(cT * 16 + lr) * 544 + ko;
      #pragma unroll
      for (int kb = 0; kb < 17; ++kb) {
        bfrag a = *(const bfrag*)(sm + (w * 16 + lr) * 544 + kb * 32 + ko);
        bfrag bb = *(const bfrag*)(bp + kb * 32);
        acc = MFMA(a, bb, acc, 0, 0, 0);
      }
      int nc = cT * 16 + lr;
      #pragma unroll
      for (int j = 0; j < 4; ++j) {
        int b = B0 + bH * 32 + w * 16 + (l >> 4) * 4 + j;
        if (nc < 128) afstore(out_mu + (size_t)b * 128 + nc, acc[j]);
        else afstore(out_ps + (size_t)b * 128 + nc - 128, acc[j]);
      }
    }
  }
  garrive(FA, m, 258, tid);

  // Lphase C: z = mu + exp(ps/2)*eps -> Az
  gwait(FA, 258, tid, &sdead);
  {
    int r = tid >> 7, zj = tid & 127;
    int b = B0 + m * 2 + r;
    float mu = afload(out_mu + (size_t)b * 128 + zj);
    float ps = afload(out_ps + (size_t)b * 128 + zj);
    float z = mu + __expf(0.5f * ps) * eps[zj];
    lat_z[r * 128 + zj] = f2bf(z);
  }
  __syncthreads();
  if (tid < 80) {
    int r = tid / 40, u = tid % 40;
    u64 pv = 0;
    #pragma unroll
    for (int q = 0; q < 4; ++q) {
      int c = u * 4 + q;
      u16 x;
      if (c < 128) x = lat_z[r * 128 + c];
      else if (c == 128) x = 0x3F80;
      else x = 0;
      pv |= ((u64)x) << (q * 16);
    }
    astore((u64*)(Az + (size_t)(B0 + m * 2 + r) * 160) + u, pv);
  }
  garrive(FA, m, 259, tid);

  // Lphase D: h0 = tanh(Az @ WH0^T) -> hdec slot 1; z into regs for decoder
  gwait(FA, 259, tid, &sdead);
  u64 zreg0[4], zreg1[4];
  {
    int r = tid >> 3;
    #pragma unroll
    for (int i = 0; i < 4; ++i) {
      int uu = (tid & 7) * 4 + i;
      zreg0[i] = aload((const u64*)(Az + (size_t)(B0 + r) * 160) + uu);
      zreg1[i] = aload((const u64*)(Az + (size_t)(B0 + 32 + r) * 160) + uu);
    }
  }
  {
    const u64* src = (const u64*)(Az + (size_t)B0 * 160);
    u64 sv[10];
    #pragma unroll
    for (int i = 0; i < 10; ++i) sv[i] = aload(src + i * 256 + tid);
    #pragma unroll
    for (int i = 0; i < 10; ++i) *(u64*)(sm + (i * 256 + tid) * 4) = sv[i];
    __syncthreads();
    f32x4 acc = {0.f, 0.f, 0.f, 0.f};
    const u16* bp = WH0P + (size_t)(m * 16 + lr) * 160 + ko;
    #pragma unroll
    for (int kb = 0; kb < 5; ++kb) {
      bfrag a = *(const bfrag*)(sm + (w * 16 + lr) * 160 + kb * 32 + ko);
      bfrag bb = *(const bfrag*)(bp + kb * 32);
      acc = MFMA(a, bb, acc, 0, 0, 0);
    }
    #pragma unroll
    for (int j = 0; j < 4; ++j)
      hst[(w * 16 + (l >> 4) * 4 + j) * 16 + lr] = f2bf(tanh_(acc[j]));
  }
  __syncthreads();
  // decoder A-tile tail pads: cols 645..679 (645 rewritten by staging each step)
  #pragma unroll
  for (int i = 0; i < 5; ++i) {
    int idx = i * 256 + tid;
    if (idx < 1120) {
      int row = idx / 35, c = idx % 35;
      sm[row * 680 + 645 + c] = (c == 0) ? 0x3F80 : 0;
    }
  }
  {
    int row = tid >> 2, q = tid & 3;
    u64 v = *(const u64*)(hst + row * 16 + q * 4);
    astore((u64*)(hdec + 262144 + (size_t)(B0 + row) * 512 + m * 16) + q, v);
  }
  garrive(FA, m, 260, tid);
  if (tid == 0)
    __hip_atomic_store(FB + m, 257, __ATOMIC_RELAXED, __HIP_MEMORY_SCOPE_AGENT);

  // ---------------- decoder: 256 steps x 2 half-chains + fused y ----------------
  float c_dec00 = 0.f, c_dec01 = 0.f, c_dec10 = 0.f, c_dec11 = 0.f;
  #pragma unroll 1
  for (int t = 0; t < 256; ++t) {
    #pragma unroll
    for (int X = 0; X < 2; ++X) {
      int* F = X ? FB : FA;
      int base = X ? 257 : 260;
      gwait(F, base + t, tid, &sdead);
      const u64* hs = (const u64*)(hdec + (size_t)((t + 1) & 1) * 262144 +
                                   (size_t)(B0 + X * 32) * 512);
      u64 hv[16];
      #pragma unroll
      for (int i = 0; i < 16; ++i) hv[i] = aload(hs + i * 256 + tid);
      #pragma unroll
      for (int i = 0; i < 16; ++i) {
        int idx = i * 256 + tid;
        *(u64*)(sm + (idx >> 7) * 680 + (idx & 127) * 4) = hv[i];
      }
      {
        int r = tid >> 3;
        #pragma unroll
        for (int i = 0; i < 4; ++i) {
          int uu = (tid & 7) * 4 + i;
          *(u64*)(sm + r * 680 + 512 + uu * 4) = (X == 0) ? zreg0[i] : zreg1[i];
        }
      }
      if (tid < 64) {   // x|bias cols 640..647
        int row = tid >> 1, q = tid & 1;
        u64 v;
        if (t == 0) v = q ? 0x000000003F800000ULL : 0x00003F8000000000ULL;  // s0,bias
        else v = *(const u64*)(SXD + ((size_t)((t - 1) * 512 + B0 + X * 32 + row)) * 8 + q * 4);
        *(u64*)(sm + row * 680 + 640 + q * 4) = v;
      }
      __syncthreads();
      const int mtd = w & 1, nb = (w >> 1) * 2;
      const bool doy = (m < 8) && (w < 2) && (t > 0);
      f32x4 acc0 = {0.f, 0.f, 0.f, 0.f}, acc1 = {0.f, 0.f, 0.f, 0.f}, accy = {0.f, 0.f, 0.f, 0.f};
      #pragma unroll
      for (int kb = 0; kb < 21; ++kb) {
        bfrag a  = *(const bfrag*)(sm + (mtd * 16 + lr) * 680 + kb * 32 + ko);
        bfrag b0 = *(const bfrag*)(sm + 21760 + kb * 2048 + nb * 512 + l * 8);
        bfrag b1 = *(const bfrag*)(sm + 21760 + kb * 2048 + (nb + 1) * 512 + l * 8);
        acc0 = MFMA(a, b0, acc0, 0, 0, 0);
        acc1 = MFMA(a, b1, acc1, 0, 0, 0);
        if (kb < 16 && doy) {
          bfrag by = *(const bfrag*)(sm + 64768 + kb * 512 + l * 8);
          accy = MFMA(a, by, accy, 0, 0, 0);
        }
      }
      if (doy && gcol < 123) {
        int brow = B0 + X * 32 + w * 16 + (l >> 4) * 4;
        #pragma unroll
        for (int j = 0; j < 4; ++j)
          out[((size_t)(brow + j) * 256 + (t - 1)) * 123 + gcol] = accy[j] + bd;
      }
      #pragma unroll
      for (int j = 0; j < 4; ++j) {
        int grow = mtd * 16 + (l >> 4) * 4 + j;
        gbuf[grow * 66 + nb * 16 + lr] = acc0[j];
        gbuf[grow * 66 + (nb + 1) * 16 + lr] = acc1[j];
      }
      __syncthreads();
      #pragma unroll
      for (int p = 0; p < 2; ++p) {
        int idx = p * 256 + tid;
        int bl = idx >> 4, u = idx & 15;
        float gi = gbuf[bl * 66 + u * 4 + 0], gf = gbuf[bl * 66 + u * 4 + 1];
        float gg = gbuf[bl * 66 + u * 4 + 2], go = gbuf[bl * 66 + u * 4 + 3];
        float cprev = (X == 0) ? (p == 0 ? c_dec00 : c_dec01) : (p == 0 ? c_dec10 : c_dec11);
        float c = sigm(gf) * cprev + sigm(gi) * tanh_(gg);
        if (X == 0) { if (p == 0) c_dec00 = c; else c_dec01 = c; }
        else        { if (p == 0) c_dec10 = c; else c_dec11 = c; }
        hst[bl * 16 + u] = f2bf(sigm(go) * tanh_(c));
      }
      __syncthreads();
      if (tid < 128) {
        int row = tid >> 2, q = tid & 3;
        u64 v = *(const u64*)(hst + row * 16 + q * 4);
        astore((u64*)(hdec + (size_t)(t & 1) * 262144 +
                      (size_t)(B0 + X * 32 + row) * 512 + m * 16) + q, v);
      }
      garrive(F, m, base + t + 1, tid);
    }
  }

  // extra epoch: y_255 from h(255) (slot 1)
  gwait(FA, 516, tid, &sdead);
  gwait(FB, 513, tid, &sdead);
  #pragma unroll
  for (int X = 0; X < 2; ++X) {
    const u64* hsrc = (const u64*)(hdec + 262144 + (size_t)(B0 + X * 32) * 512);
    u64 hv[16];
    #pragma unroll
    for (int i = 0; i < 16; ++i) hv[i] = aload(hsrc + i * 256 + tid);
    #pragma unroll
    for (int i = 0; i < 16; ++i) {
      int idx = i * 256 + tid;
      *(u64*)(sm + (idx >> 7) * 680 + (idx & 127) * 4) = hv[i];
    }
    __syncthreads();
    if (m < 8 && w < 2) {
      f32x4 accy = {0.f, 0.f, 0.f, 0.f};
      #pragma unroll
      for (int kb = 0; kb < 16; ++kb) {
        bfrag a = *(const bfrag*)(sm + (w * 16 + lr) * 680 + kb * 32 + ko);
        bfrag by = *(const bfrag*)(sm + 64768 + kb * 512 + l * 8);
        accy = MFMA(a, by, accy, 0, 0, 0);
      }
      if (gcol < 123) {
        int brow = B0 + X * 32 + w * 16 + (l >> 4) * 4;
        #pragma unroll
        for (int j = 0; j < 4; ++j)
          out[((size_t)(brow + j) * 256 + 255) * 123 + gcol] = accy[j] + bd;
      }
    }
    __syncthreads();
  }
}

// ============================================================= MDN in place
__global__ __launch_bounds__(64) void mdn_final(float* __restrict__ out) {
  __shared__ float rows[64 * 123];
  const int tid = threadIdx.x;
  float4* g4 = (float4*)(out + (size_t)blockIdx.x * 64 * 123);
  #pragma unroll
  for (int i = 0; i < 31; ++i) {
    int c = i * 64 + tid;
    if (c < 1968) ((float4*)rows)[c] = g4[c];
  }
  __syncthreads();
  {
    float* r = rows + tid * 123;
    float m1 = -1e30f;
    #pragma unroll
    for (int k = 0; k < 20; ++k) m1 = fmaxf(m1, r[6 * k]);
    float s1 = 0.f;
    #pragma unroll
    for (int k = 0; k < 20; ++k) s1 += __expf(r[6 * k] - m1);
    float i1 = 1.f / s1;
    #pragma unroll
    for (int k = 0; k < 20; ++k) {
      r[6 * k] = __expf(r[6 * k] - m1) * i1;
      r[6 * k + 3] = __expf(r[6 * k + 3]);
      r[6 * k + 4] = __expf(r[6 * k + 4]);
      r[6 * k + 5] = tanh_(r[6 * k + 5]);
    }
    float p0 = r[120], p1 = r[121], p2 = r[122];
    float mp = fmaxf(p0, fmaxf(p1, p2));
    float e0 = __expf(p0 - mp), e1 = __expf(p1 - mp), e2 = __expf(p2 - mp);
    float ip = 1.f / (e0 + e1 + e2);
    r[120] = e0 * ip; r[121] = e1 * ip; r[122] = e2 * ip;
  }
  __syncthreads();
  #pragma unroll
  for (int i = 0; i < 31; ++i) {
    int c = i * 64 + tid;
    if (c < 1968) g4[c] = ((float4*)rows)[c];
  }
}

extern "C" void kernel_launch(void* const* d_in, const int* in_sizes, int n_in,
                              void* d_out, int out_size, void* d_ws, size_t ws_size,
                              hipStream_t stream) {
  const float* s       = (const float*)d_in[0];
  const float* eps     = (const float*)d_in[1];
  const float* Wih_f   = (const float*)d_in[2];
  const float* Whh_f   = (const float*)d_in[3];
  const float* bih_f   = (const float*)d_in[4];
  const float* bhh_f   = (const float*)d_in[5];
  const float* Wih_b   = (const float*)d_in[6];
  const float* bih_b   = (const float*)d_in[8];
  const float* bhh_b   = (const float*)d_in[9];
  const float* W_sigma = (const float*)d_in[10];
  const float* b_sigma = (const float*)d_in[11];
  const float* W_mu    = (const float*)d_in[12];
  const float* b_mu    = (const float*)d_in[13];
  const float* W_h0    = (const float*)d_in[14];
  const float* b_h0    = (const float*)d_in[15];
  const float* Wih_d   = (const float*)d_in[16];
  const float* Whh_d   = (const float*)d_in[17];
  const float* bih_d   = (const float*)d_in[18];
  const float* bhh_d   = (const float*)d_in[19];
  const float* W_dec   = (const float*)d_in[20];
  const float* b_dec   = (const float*)d_in[21];

  char* ws = (char*)d_ws;
  int* FLAGS  = (int*)(ws + OFF_FLAGS);
  u16* HENC   = (u16*)(ws + OFF_HENC);
  u16* WENCP  = (u16*)(ws + OFF_WENC);
  u16* WDECP  = (u16*)(ws + OFF_WDEC);
  u16* WYP    = (u16*)(ws + OFF_WY);
  u16* WMSP   = (u16*)(ws + OFF_WMS);
  u16* WH0P   = (u16*)(ws + OFF_WH0);
  u16* HDEC   = (u16*)(ws + OFF_HDEC);
  u16* HLAT   = (u16*)(ws + OFF_HLAT);
  u16* AZ     = (u16*)(ws + OFF_AZ);
  u16* SXD    = (u16*)(ws + OFF_SX);
  float* out  = (float*)d_out;

  // reset flags + zero encoder h(-1) every launch (graph-replay safe)
  hipMemsetAsync(ws, 0, 4096 + 524288, stream);

  pack_wenc<<<1152, 256, 0, stream>>>(Whh_f, Wih_f, bih_f, bhh_f, WENCP);
  pack_wdec<<<5376, 256, 0, stream>>>(Whh_d, Wih_d, bih_d, bhh_d, WDECP);
  pack_wy<<<256, 256, 0, stream>>>(W_dec, WYP);
  pack_wms<<<544, 256, 0, stream>>>(W_mu, b_mu, W_sigma, b_sigma, WMSP);
  pack_wh0<<<320, 256, 0, stream>>>(W_h0, b_h0, WH0P);
  pack_sx<<<4096, 256, 0, stream>>>(s, SXD);

  rnn_persist<<<256, 256, 0, stream>>>(FLAGS, HENC, WENCP, WDECP, WYP, WMSP, WH0P,
                                       HDEC, HLAT, AZ, SXD, s, eps,
                                       Wih_b, bih_b, bhh_b, b_dec, out);

  mdn_final<<<2048, 64, 0, stream>>>(out);

  (void)in_sizes; (void)n_in; (void)out_size; (void)ws_size;
}

// Round 7
// 2942.359 us; speedup vs baseline: 1.0166x; 1.0166x over previous
//
#include <hip/hip_runtime.h>

typedef unsigned short u16;
typedef unsigned int u32;
typedef unsigned long long u64;
typedef __attribute__((ext_vector_type(8))) short bfrag;
typedef __attribute__((ext_vector_type(4))) float f32x4;

#define MFMA __builtin_amdgcn_mfma_f32_16x16x32_bf16

// ---------------- ws layout (bytes) ----------------
#define OFF_FLAGS 0ull            //  4096 (latent barriers only)
#define OFF_HENCW 4096ull         //  1048576  u64[2][512][128]  {2 bf16 | tag}
#define OFF_HDECW 1052672ull      //  2097152  u64[2][512][256]
#define MEMSET_BYTES 3149824ull
#define OFF_WENC  3149824ull      //  589824
#define OFF_WDEC  3739648ull      //  2752512
#define OFF_WY    6492160ull      //  131072
#define OFF_WMS   6623232ull      //  278528
#define OFF_WH0   6901760ull      //  163840
#define OFF_HLAT  7065600ull      //  557056
#define OFF_AZ    7622656ull      //  163840
#define OFF_SX    7786496ull      //  2097152  u16[256][512][8]

__device__ __forceinline__ u16 f2bf(float f) {
  union { float f; unsigned int i; } v; v.f = f;
  unsigned int r = v.i + 0x7fffu + ((v.i >> 16) & 1u);
  return (u16)(r >> 16);
}
__device__ __forceinline__ float sigm(float x) { return 1.0f / (1.0f + __expf(-x)); }
__device__ __forceinline__ float tanh_(float x) {
  float a = fabsf(x);
  float e = __expf(-2.0f * a);
  float r = (1.0f - e) / (1.0f + e);
  return x < 0.0f ? -r : r;
}

// relaxed agent-scope movers: MALL-coherent, no cache-maintenance fences (r4/r6-proven)
__device__ __forceinline__ u64 aload(const u64* p) {
  return __hip_atomic_load(p, __ATOMIC_RELAXED, __HIP_MEMORY_SCOPE_AGENT);
}
__device__ __forceinline__ void astore(u64* p, u64 v) {
  __hip_atomic_store(p, v, __ATOMIC_RELAXED, __HIP_MEMORY_SCOPE_AGENT);
}
__device__ __forceinline__ float afload(const float* p) {
  return __hip_atomic_load(p, __ATOMIC_RELAXED, __HIP_MEMORY_SCOPE_AGENT);
}
__device__ __forceinline__ void afstore(float* p, float v) {
  __hip_atomic_store(p, v, __ATOMIC_RELAXED, __HIP_MEMORY_SCOPE_AGENT);
}

// latent-only group barrier (r6-proven)
__device__ __forceinline__ void gwait(int* base, int ep, int tid, int* sdead) {
  if (ep > 0) {
    if (tid < 32 && *sdead == 0) {
      int* fp = base + tid;
      int spin = 0;
      while (__hip_atomic_load(fp, __ATOMIC_RELAXED, __HIP_MEMORY_SCOPE_AGENT) < ep) {
        __builtin_amdgcn_s_sleep(1);
        if (++spin > (1 << 18)) { *sdead = 1; break; }
      }
    }
  }
  __syncthreads();
  asm volatile("" ::: "memory");
}
__device__ __forceinline__ void garrive(int* base, int m, int ep, int tid) {
  asm volatile("s_waitcnt vmcnt(0)" ::: "memory");
  __syncthreads();
  if (tid == 0)
    __hip_atomic_store(base + m, ep, __ATOMIC_RELAXED, __HIP_MEMORY_SCOPE_AGENT);
}

// ============================================================= prep packs
__global__ void pack_wenc(const float* __restrict__ Whh, const float* __restrict__ Wih,
                          const float* __restrict__ bi, const float* __restrict__ bh,
                          u16* __restrict__ out) {
  int idx = blockIdx.x * 256 + threadIdx.x;
  if (idx >= 294912) return;
  int m = idx / 9216, within = idx % 9216;
  int kb = within >> 10, rest = within & 1023;
  int ng = rest >> 9, l = (rest >> 3) & 63, j = rest & 7;
  int nl = ng * 16 + (l & 15);
  int u = nl >> 2, g = nl & 3;
  int row = g * 256 + m * 8 + u;
  int k = kb * 32 + (l >> 4) * 8 + j;
  float v = 0.f;
  if (k < 256) v = Whh[row * 256 + k];
  else if (k < 261) v = Wih[row * 5 + (k - 256)];
  else if (k == 261) v = bi[row] + bh[row];
  out[idx] = f2bf(v);
}

__global__ void pack_wdec(const float* __restrict__ Whh, const float* __restrict__ Wih,
                          const float* __restrict__ bi, const float* __restrict__ bh,
                          u16* __restrict__ out) {
  int idx = blockIdx.x * 256 + threadIdx.x;
  if (idx >= 1376256) return;
  int m = idx / 43008, within = idx % 43008;
  int kb = within >> 11, rest = within & 2047;
  int w = rest >> 9, l = (rest >> 3) & 63, j = rest & 7;
  int nl = w * 16 + (l & 15);
  int u = nl >> 2, g = nl & 3;
  int row = g * 512 + m * 16 + u;
  int k = kb * 32 + (l >> 4) * 8 + j;
  float v = 0.f;
  if (k < 512) v = Whh[row * 512 + k];
  else if (k < 640) v = Wih[row * 133 + 5 + (k - 512)];
  else if (k < 645) v = Wih[row * 133 + (k - 640)];
  else if (k == 645) v = bi[row] + bh[row];
  out[idx] = f2bf(v);
}

__global__ void pack_wy(const float* __restrict__ Wd, u16* __restrict__ out) {
  int idx = blockIdx.x * 256 + threadIdx.x;
  if (idx >= 65536) return;
  int m = idx >> 13, within = idx & 8191;
  int kb = within >> 9, rest = within & 511;
  int l = rest >> 3, j = rest & 7;
  int row = m * 16 + (l & 15);
  int k = kb * 32 + (l >> 4) * 8 + j;
  float v = (row < 123 && k < 512) ? Wd[row * 512 + k] : 0.f;
  out[idx] = f2bf(v);
}

__global__ void pack_wms(const float* __restrict__ Wmu, const float* __restrict__ bmu,
                         const float* __restrict__ Wsig, const float* __restrict__ bsig,
                         u16* __restrict__ out) {
  int idx = blockIdx.x * 256 + threadIdx.x;
  if (idx >= 139264) return;
  int r = idx / 544, k = idx % 544;
  float v = 0.f;
  if (r < 128) {
    if (k < 512) v = Wmu[r * 512 + k];
    else if (k == 512) v = bmu[r];
  } else {
    int r2 = r - 128;
    if (k < 512) v = Wsig[r2 * 512 + k];
    else if (k == 512) v = bsig[r2];
  }
  out[idx] = f2bf(v);
}

__global__ void pack_wh0(const float* __restrict__ Wh0, const float* __restrict__ bh0,
                         u16* __restrict__ out) {
  int idx = blockIdx.x * 256 + threadIdx.x;
  if (idx >= 81920) return;
  int r = idx / 160, k = idx % 160;
  float v = 0.f;
  if (k < 128) v = Wh0[r * 128 + k];
  else if (k == 128) v = bh0[r];
  out[idx] = f2bf(v);
}

// s -> bf16 [t][b][8]: 0..4 = x, 5 = 1.0 (bias), 6..7 = 0
__global__ void pack_sx(const float* __restrict__ s, u16* __restrict__ out) {
  int idx = blockIdx.x * 256 + threadIdx.x;
  if (idx >= 1048576) return;
  int j = idx & 7, b = (idx >> 3) & 511, t = idx >> 12;
  u16 v;
  if (j < 5) v = f2bf(s[((size_t)b * 256 + t) * 5 + j]);
  else v = (j == 5) ? (u16)0x3F80 : (u16)0;
  out[idx] = v;
}

// ============================================================= persistent
// group g = blk & 7, member m = blk >> 3. Group owns batch [g*64, g*64+64).
// Exchange words: {lo32 = 2 bf16, hi32 = step tag}. enc tag(t)=t+1; dec tag(t)=t+2, h0 tag=1.
__global__ __launch_bounds__(256, 1) void rnn_persist(
    int* __restrict__ flags, u64* __restrict__ hencW, u64* __restrict__ hdecW,
    const u16* __restrict__ WENCP, const u16* __restrict__ WDECP,
    const u16* __restrict__ WYP, const u16* __restrict__ WMSP, const u16* __restrict__ WH0P,
    u16* __restrict__ hlat, u16* __restrict__ Az, const u16* __restrict__ SXD,
    const float* __restrict__ s, const float* __restrict__ eps,
    const float* __restrict__ Wih_b, const float* __restrict__ bih_b,
    const float* __restrict__ bhh_b,
    const float* __restrict__ b_dec, float* __restrict__ out)
{
  __shared__ __align__(16) u16 sm[72960];
  __shared__ __align__(16) float gbuf[2112];
  __shared__ __align__(16) u16 hst[1024];
  __shared__ int sdead;

  const int tid = threadIdx.x;
  const int blk = blockIdx.x;
  const int g = blk & 7;
  const int m = blk >> 3;
  const int B0 = g * 64;
  const int w = tid >> 6, l = tid & 63;
  const int lr = l & 15, ko = (l >> 4) * 8;
  int* FG = flags + g * 64;
  const u32* hst32 = (const u32*)hst;

  float* out_mu = out + 16121856;
  float* out_ps = out + 16187392;

  const int gcol = m * 16 + lr;
  float bd = 0.f;
  if (m < 8 && gcol < 123) bd = b_dec[gcol];

  if (tid == 0) sdead = 0;
  // zero encoder A region
  {
    bfrag zz = {0, 0, 0, 0, 0, 0, 0, 0};
    #pragma unroll
    for (int i = 0; i < 5; ++i) {
      int c = i * 256 + tid;
      if (c < 1184) *(bfrag*)(sm + c * 8) = zz;
    }
  }
  // encoder weight slice -> LDS
  {
    const u16* src = WENCP + (size_t)m * 9216;
    #pragma unroll
    for (int i = 0; i < 5; ++i) {
      int c = i * 256 + tid;
      if (c < 1152) *(bfrag*)(sm + 21760 + c * 8) = *(const bfrag*)(src + c * 8);
    }
  }
  __syncthreads();

  u64 hv[32];
  u64 sxv = 0;

  // ---------------- encoder: 512 epochs (t-major, halves X inner), flag-free ----------------
  // prologue loads e=0 (X=0,t=0): slot1, tag 0 (memset zeros)
  {
    const u64* base = hencW + 65536 + (size_t)B0 * 128;
    #pragma unroll
    for (int i = 0; i < 16; ++i) hv[i] = aload(base + i * 256 + tid);
    if (tid < 64)
      sxv = *(const u64*)(SXD + (size_t)(B0 + (tid >> 1)) * 8 + (tid & 1) * 4);
  }
  float c_enc0 = 0.f, c_enc1 = 0.f;
  #pragma unroll 1
  for (int e = 0; e < 512; ++e) {
    const int X = e & 1, t = e >> 1;
    {  // validate tags == t (= enc tag(t-1))
      const u64* base = hencW + (size_t)((t + 1) & 1) * 65536 + (size_t)(B0 + X * 32) * 128;
      int tries = 0;
      while (true) {
        bool ok = true;
        #pragma unroll
        for (int i = 0; i < 16; ++i) ok &= ((u32)(hv[i] >> 32) == (u32)t);
        if (__all(ok)) break;
        if (++tries > (1 << 14)) break;
        __builtin_amdgcn_s_sleep(1);
        #pragma unroll
        for (int i = 0; i < 16; ++i) hv[i] = aload(base + i * 256 + tid);
      }
    }
    #pragma unroll
    for (int i = 0; i < 16; ++i) {
      int idx = i * 256 + tid;
      *(u32*)((char*)sm + (idx >> 7) * 592 + (idx & 127) * 4) = (u32)hv[i];
    }
    if (tid < 64) *(u64*)(sm + (tid >> 1) * 296 + 256 + (tid & 1) * 4) = sxv;
    __syncthreads();
    const int mt = w >> 1, ng = w & 1;
    f32x4 acc = {0.f, 0.f, 0.f, 0.f};
    #pragma unroll
    for (int kb = 0; kb < 9; ++kb) {
      bfrag a = *(const bfrag*)(sm + (mt * 16 + lr) * 296 + kb * 32 + ko);
      bfrag bw = *(const bfrag*)(sm + 21760 + (kb * 2 + ng) * 512 + l * 8);
      acc = MFMA(a, bw, acc, 0, 0, 0);
    }
    #pragma unroll
    for (int j = 0; j < 4; ++j)
      gbuf[(mt * 16 + (l >> 4) * 4 + j) * 33 + ng * 16 + lr] = acc[j];
    __syncthreads();
    {
      int bl = tid >> 3, u = tid & 7;
      float gi = gbuf[bl * 33 + u * 4 + 0], gf = gbuf[bl * 33 + u * 4 + 1];
      float gg = gbuf[bl * 33 + u * 4 + 2], go = gbuf[bl * 33 + u * 4 + 3];
      float cprev = (X == 0) ? c_enc0 : c_enc1;
      float c = sigm(gf) * cprev + sigm(gi) * tanh_(gg);
      if (X == 0) c_enc0 = c; else c_enc1 = c;
      hst[bl * 8 + u] = f2bf(sigm(go) * tanh_(c));
    }
    __syncthreads();
    if (tid < 128) {  // tagged store: tag t+1
      int row = tid >> 2, j = tid & 3;
      u64 wv = (u64)hst32[row * 4 + j] | ((u64)(u32)(t + 1) << 32);
      astore(hencW + (size_t)(t & 1) * 65536 + (size_t)(B0 + X * 32 + row) * 128 + 4 * m + j, wv);
    }
    if (e < 511) {  // prefetch e+1
      int Xn = (e + 1) & 1, tn = (e + 1) >> 1;
      const u64* base = hencW + (size_t)((tn + 1) & 1) * 65536 + (size_t)(B0 + Xn * 32) * 128;
      #pragma unroll
      for (int i = 0; i < 16; ++i) hv[i] = aload(base + i * 256 + tid);
      if (tid < 64)
        sxv = *(const u64*)(SXD + (size_t)(tn * 512 + B0 + Xn * 32 + (tid >> 1)) * 8 + (tid & 1) * 4);
    }
  }

  // ---------------- latent (flag-protected, one-off) ----------------
  u16* lat_hf = (u16*)gbuf;          // [2][256]
  u16* lat_hb = (u16*)gbuf + 512;    // [2][256]
  u16* lat_z  = (u16*)gbuf + 1024;   // [2][128]
  __syncthreads();

  {  // decoder gate weights -> LDS (overlaps latent math)
    const u16* src = WDECP + (size_t)m * 43008;
    #pragma unroll 1
    for (int i = 0; i < 21; ++i) {
      int c = i * 256 + tid;
      *(bfrag*)(sm + 21760 + c * 8) = *(const bfrag*)(src + c * 8);
    }
  }
  if (m < 8) {
    const u16* src = WYP + (size_t)m * 8192;
    #pragma unroll
    for (int i = 0; i < 4; ++i) {
      int c = i * 256 + tid;
      *(bfrag*)(sm + 64768 + c * 8) = *(const bfrag*)(src + c * 8);
    }
  }
  // L-A: read tagged henc final (tag 256) + backward LSTM; build hlat
  {
    int r = tid >> 7, wc = tid & 127;
    const u64* p = hencW + 65536 + (size_t)(B0 + m * 2 + r) * 128 + wc;
    u64 v = aload(p);
    int tries = 0;
    while (!__all((u32)(v >> 32) == 256u)) {
      if (++tries > (1 << 14)) break;
      __builtin_amdgcn_s_sleep(1);
      v = aload(p);
    }
    ((u32*)lat_hf)[r * 128 + wc] = (u32)v;
  }
  #pragma unroll
  for (int r = 0; r < 2; ++r) {
    int b = B0 + m * 2 + r;
    const float* xr = s + ((size_t)b * 256 + 255) * 5;
    float x0 = xr[0], x1 = xr[1], x2 = xr[2], x3 = xr[3], x4 = xr[4];
    int n = tid;
    float gv[4];
    #pragma unroll
    for (int gg = 0; gg < 4; ++gg) {
      int row = gg * 256 + n;
      gv[gg] = bih_b[row] + bhh_b[row] + x0 * Wih_b[row * 5] + x1 * Wih_b[row * 5 + 1] +
               x2 * Wih_b[row * 5 + 2] + x3 * Wih_b[row * 5 + 3] + x4 * Wih_b[row * 5 + 4];
    }
    float c = sigm(gv[0]) * tanh_(gv[2]);
    lat_hb[r * 256 + n] = f2bf(sigm(gv[3]) * tanh_(c));
  }
  __syncthreads();
  #pragma unroll
  for (int it = 0; it < 2; ++it) {
    int idx = it * 256 + tid;
    if (idx < 272) {
      int rr = idx / 136, u = idx % 136;
      u64 pv = 0;
      #pragma unroll
      for (int q = 0; q < 4; ++q) {
        int c = u * 4 + q;
        u16 x;
        if (c < 256) x = lat_hf[rr * 256 + c];
        else if (c < 512) x = lat_hb[rr * 256 + c - 256];
        else if (c == 512) x = 0x3F80;
        else x = 0;
        pv |= ((u64)x) << (q * 16);
      }
      astore((u64*)(hlat + (size_t)(B0 + m * 2 + rr) * 544) + u, pv);
    }
  }
  garrive(FG, m, 1, tid);
  gwait(FG, 1, tid, &sdead);
  // L-B: [mu|presig] = hlat @ WMS^T -> d_out
  {
    const int bH = m >> 4, cT = m & 15;
    const u64* src = (const u64*)(hlat + (size_t)(B0 + bH * 32) * 544);
    u64 sv[17];
    #pragma unroll
    for (int i = 0; i < 17; ++i) sv[i] = aload(src + i * 256 + tid);
    #pragma unroll
    for (int i = 0; i < 17; ++i) *(u64*)(sm + (i * 256 + tid) * 4) = sv[i];
    __syncthreads();
    if (w < 2) {
      f32x4 acc = {0.f, 0.f, 0.f, 0.f};
      const u16* bp = WMSP + (size_t)(cT * 16 + lr) * 544 + ko;
      #pragma unroll
      for (int kb = 0; kb < 17; ++kb) {
        bfrag a = *(const bfrag*)(sm + (w * 16 + lr) * 544 + kb * 32 + ko);
        bfrag bb = *(const bfrag*)(bp + kb * 32);
        acc = MFMA(a, bb, acc, 0, 0, 0);
      }
      int nc = cT * 16 + lr;
      #pragma unroll
      for (int j = 0; j < 4; ++j) {
        int b = B0 + bH * 32 + w * 16 + (l >> 4) * 4 + j;
        if (nc < 128) afstore(out_mu + (size_t)b * 128 + nc, acc[j]);
        else afstore(out_ps + (size_t)b * 128 + nc - 128, acc[j]);
      }
    }
  }
  garrive(FG, m, 2, tid);
  gwait(FG, 2, tid, &sdead);
  // L-C: z = mu + exp(ps/2)*eps -> Az
  {
    int r = tid >> 7, zj = tid & 127;
    int b = B0 + m * 2 + r;
    float mu = afload(out_mu + (size_t)b * 128 + zj);
    float ps = afload(out_ps + (size_t)b * 128 + zj);
    float z = mu + __expf(0.5f * ps) * eps[zj];
    lat_z[r * 128 + zj] = f2bf(z);
  }
  __syncthreads();
  if (tid < 80) {
    int r = tid / 40, u = tid % 40;
    u64 pv = 0;
    #pragma unroll
    for (int q = 0; q < 4; ++q) {
      int c = u * 4 + q;
      u16 x;
      if (c < 128) x = lat_z[r * 128 + c];
      else if (c == 128) x = 0x3F80;
      else x = 0;
      pv |= ((u64)x) << (q * 16);
    }
    astore((u64*)(Az + (size_t)(B0 + m * 2 + r) * 160) + u, pv);
  }
  garrive(FG, m, 3, tid);
  gwait(FG, 3, tid, &sdead);
  // L-D: zregs; h0 = tanh(Az @ WH0^T) -> hdecW slot1 tag 1; decoder pads
  u64 zreg0[4], zreg1[4];
  {
    int r = tid >> 3;
    #pragma unroll
    for (int i = 0; i < 4; ++i) {
      int uu = (tid & 7) * 4 + i;
      zreg0[i] = aload((const u64*)(Az + (size_t)(B0 + r) * 160) + uu);
      zreg1[i] = aload((const u64*)(Az + (size_t)(B0 + 32 + r) * 160) + uu);
    }
  }
  {
    const u64* src = (const u64*)(Az + (size_t)B0 * 160);
    u64 sv[10];
    #pragma unroll
    for (int i = 0; i < 10; ++i) sv[i] = aload(src + i * 256 + tid);
    #pragma unroll
    for (int i = 0; i < 10; ++i) *(u64*)(sm + (i * 256 + tid) * 4) = sv[i];
    __syncthreads();
    f32x4 acc = {0.f, 0.f, 0.f, 0.f};
    const u16* bp = WH0P + (size_t)(m * 16 + lr) * 160 + ko;
    #pragma unroll
    for (int kb = 0; kb < 5; ++kb) {
      bfrag a = *(const bfrag*)(sm + (w * 16 + lr) * 160 + kb * 32 + ko);
      bfrag bb = *(const bfrag*)(bp + kb * 32);
      acc = MFMA(a, bb, acc, 0, 0, 0);
    }
    #pragma unroll
    for (int j = 0; j < 4; ++j)
      hst[(w * 16 + (l >> 4) * 4 + j) * 16 + lr] = f2bf(tanh_(acc[j]));
  }
  __syncthreads();
  #pragma unroll
  for (int i = 0; i < 2; ++i) {  // tagged h0 store, tag 1
    int idx = i * 256 + tid;
    int row = idx >> 3, j = idx & 7;
    u64 wv = (u64)hst32[row * 8 + j] | (1ull << 32);
    astore(hdecW + 131072 + (size_t)(B0 + row) * 256 + 8 * m + j, wv);
  }
  // decoder A-tile pads: cols 648..679 = 0 (bias col 645 comes with x-word each step)
  #pragma unroll
  for (int i = 0; i < 4; ++i) {
    int idx = i * 256 + tid;
    if (idx < 1024) {
      int row = idx >> 5, c = idx & 31;
      sm[row * 680 + 648 + c] = 0;
    }
  }
  garrive(FG, m, 4, tid);
  gwait(FG, 4, tid, &sdead);

  // ---------------- decoder: 512 epochs, flag-free, fused y ----------------
  // prologue loads e=0 (X=0,t=0): slot1, tag 1 (h0)
  {
    const u64* base = hdecW + 131072 + (size_t)B0 * 256;
    #pragma unroll
    for (int i = 0; i < 32; ++i) hv[i] = aload(base + i * 256 + tid);
    if (tid < 64)
      sxv = *(const u64*)(SXD + (size_t)(B0 + (tid >> 1)) * 8 + (tid & 1) * 4);
  }
  float c00 = 0.f, c01 = 0.f, c10 = 0.f, c11 = 0.f;
  #pragma unroll 1
  for (int e = 0; e < 512; ++e) {
    const int X = e & 1, t = e >> 1;
    {  // validate tags == t+1 (= dec tag(t-1))
      const u64* base = hdecW + (size_t)((t + 1) & 1) * 131072 + (size_t)(B0 + X * 32) * 256;
      int tries = 0;
      while (true) {
        bool ok = true;
        #pragma unroll
        for (int i = 0; i < 32; ++i) ok &= ((u32)(hv[i] >> 32) == (u32)(t + 1));
        if (__all(ok)) break;
        if (++tries > (1 << 14)) break;
        __builtin_amdgcn_s_sleep(1);
        #pragma unroll
        for (int i = 0; i < 32; ++i) hv[i] = aload(base + i * 256 + tid);
      }
    }
    #pragma unroll
    for (int i = 0; i < 32; ++i) {
      int idx = i * 256 + tid;
      *(u32*)((char*)sm + (idx >> 8) * 1360 + (idx & 255) * 4) = (u32)hv[i];
    }
    {
      int r = tid >> 3;
      #pragma unroll
      for (int i = 0; i < 4; ++i) {
        int uu = (tid & 7) * 4 + i;
        *(u64*)(sm + r * 680 + 512 + uu * 4) = (X == 0) ? zreg0[i] : zreg1[i];
      }
    }
    if (tid < 64) {  // x|bias cols 640..647
      u64 v = sxv;
      if (t == 0) v = (tid & 1) ? 0x000000003F800000ULL : 0x00003F8000000000ULL;
      *(u64*)(sm + (tid >> 1) * 680 + 640 + (tid & 1) * 4) = v;
    }
    __syncthreads();
    const int mtd = w & 1, nb = (w >> 1) * 2;
    const bool doy = (m < 8) && (w < 2) && (t > 0);
    f32x4 acc0 = {0.f, 0.f, 0.f, 0.f}, acc1 = {0.f, 0.f, 0.f, 0.f}, accy = {0.f, 0.f, 0.f, 0.f};
    #pragma unroll
    for (int kb = 0; kb < 21; ++kb) {
      bfrag a  = *(const bfrag*)(sm + (mtd * 16 + lr) * 680 + kb * 32 + ko);
      bfrag b0 = *(const bfrag*)(sm + 21760 + kb * 2048 + nb * 512 + l * 8);
      bfrag b1 = *(const bfrag*)(sm + 21760 + kb * 2048 + (nb + 1) * 512 + l * 8);
      acc0 = MFMA(a, b0, acc0, 0, 0, 0);
      acc1 = MFMA(a, b1, acc1, 0, 0, 0);
      if (kb < 16 && doy) {
        bfrag by = *(const bfrag*)(sm + 64768 + kb * 512 + l * 8);
        accy = MFMA(a, by, accy, 0, 0, 0);
      }
    }
    if (doy && gcol < 123) {
      int brow = B0 + X * 32 + w * 16 + (l >> 4) * 4;
      #pragma unroll
      for (int j = 0; j < 4; ++j)
        out[((size_t)(brow + j) * 256 + (t - 1)) * 123 + gcol] = accy[j] + bd;
    }
    #pragma unroll
    for (int j = 0; j < 4; ++j) {
      int grow = mtd * 16 + (l >> 4) * 4 + j;
      gbuf[grow * 66 + nb * 16 + lr] = acc0[j];
      gbuf[grow * 66 + (nb + 1) * 16 + lr] = acc1[j];
    }
    __syncthreads();
    #pragma unroll
    for (int p = 0; p < 2; ++p) {
      int idx = p * 256 + tid;
      int bl = idx >> 4, u = idx & 15;
      float gi = gbuf[bl * 66 + u * 4 + 0], gf = gbuf[bl * 66 + u * 4 + 1];
      float gg = gbuf[bl * 66 + u * 4 + 2], go = gbuf[bl * 66 + u * 4 + 3];
      float cprev = (X == 0) ? (p == 0 ? c00 : c01) : (p == 0 ? c10 : c11);
      float c = sigm(gf) * cprev + sigm(gi) * tanh_(gg);
      if (X == 0) { if (p == 0) c00 = c; else c01 = c; }
      else        { if (p == 0) c10 = c; else c11 = c; }
      hst[bl * 16 + u] = f2bf(sigm(go) * tanh_(c));
    }
    __syncthreads();
    {  // tagged store: tag t+2
      int row = tid >> 3, j = tid & 7;
      u64 wv = (u64)hst32[row * 8 + j] | ((u64)(u32)(t + 2) << 32);
      astore(hdecW + (size_t)(t & 1) * 131072 + (size_t)(B0 + X * 32 + row) * 256 + 8 * m + j, wv);
    }
    if (e < 511) {  // prefetch e+1
      int Xn = (e + 1) & 1, tn = (e + 1) >> 1;
      const u64* base = hdecW + (size_t)((tn + 1) & 1) * 131072 + (size_t)(B0 + Xn * 32) * 256;
      #pragma unroll
      for (int i = 0; i < 32; ++i) hv[i] = aload(base + i * 256 + tid);
      if (tid < 64) {
        int tp = (tn > 0) ? (tn - 1) : 0;
        sxv = *(const u64*)(SXD + (size_t)(tp * 512 + B0 + Xn * 32 + (tid >> 1)) * 8 + (tid & 1) * 4);
      }
    }
  }

  // tail: y_255 from h(255) (slot 1, tag 257)
  #pragma unroll 1
  for (int hh = 0; hh < 2; ++hh) {
    const u64* base = hdecW + 131072 + (size_t)(B0 + hh * 32) * 256;
    #pragma unroll
    for (int i = 0; i < 32; ++i) hv[i] = aload(base + i * 256 + tid);
    {
      int tries = 0;
      while (true) {
        bool ok = true;
        #pragma unroll
        for (int i = 0; i < 32; ++i) ok &= ((u32)(hv[i] >> 32) == 257u);
        if (__all(ok)) break;
        if (++tries > (1 << 14)) break;
        __builtin_amdgcn_s_sleep(1);
        #pragma unroll
        for (int i = 0; i < 32; ++i) hv[i] = aload(base + i * 256 + tid);
      }
    }
    #pragma unroll
    for (int i = 0; i < 32; ++i) {
      int idx = i * 256 + tid;
      *(u32*)((char*)sm + (idx >> 8) * 1360 + (idx & 255) * 4) = (u32)hv[i];
    }
    __syncthreads();
    if (m < 8 && w < 2) {
      f32x4 accy = {0.f, 0.f, 0.f, 0.f};
      #pragma unroll
      for (int kb = 0; kb < 16; ++kb) {
        bfrag a = *(const bfrag*)(sm + (w * 16 + lr) * 680 + kb * 32 + ko);
        bfrag by = *(const bfrag*)(sm + 64768 + kb * 512 + l * 8);
        accy = MFMA(a, by, accy, 0, 0, 0);
      }
      if (gcol < 123) {
        int brow = B0 + hh * 32 + w * 16 + (l >> 4) * 4;
        #pragma unroll
        for (int j = 0; j < 4; ++j)
          out[((size_t)(brow + j) * 256 + 255) * 123 + gcol] = accy[j] + bd;
      }
    }
    __syncthreads();
  }
}

// ============================================================= MDN in place
__global__ __launch_bounds__(64) void mdn_final(float* __restrict__ out) {
  __shared__ float rows[64 * 123];
  const int tid = threadIdx.x;
  float4* g4 = (float4*)(out + (size_t)blockIdx.x * 64 * 123);
  #pragma unroll
  for (int i = 0; i < 31; ++i) {
    int c = i * 64 + tid;
    if (c < 1968) ((float4*)rows)[c] = g4[c];
  }
  __syncthreads();
  {
    float* r = rows + tid * 123;
    float m1 = -1e30f;
    #pragma unroll
    for (int k = 0; k < 20; ++k) m1 = fmaxf(m1, r[6 * k]);
    float s1 = 0.f;
    #pragma unroll
    for (int k = 0; k < 20; ++k) s1 += __expf(r[6 * k] - m1);
    float i1 = 1.f / s1;
    #pragma unroll
    for (int k = 0; k < 20; ++k) {
      r[6 * k] = __expf(r[6 * k] - m1) * i1;
      r[6 * k + 3] = __expf(r[6 * k + 3]);
      r[6 * k + 4] = __expf(r[6 * k + 4]);
      r[6 * k + 5] = tanh_(r[6 * k + 5]);
    }
    float p0 = r[120], p1 = r[121], p2 = r[122];
    float mp = fmaxf(p0, fmaxf(p1, p2));
    float e0 = __expf(p0 - mp), e1 = __expf(p1 - mp), e2 = __expf(p2 - mp);
    float ip = 1.f / (e0 + e1 + e2);
    r[120] = e0 * ip; r[121] = e1 * ip; r[122] = e2 * ip;
  }
  __syncthreads();
  #pragma unroll
  for (int i = 0; i < 31; ++i) {
    int c = i * 64 + tid;
    if (c < 1968) g4[c] = ((float4*)rows)[c];
  }
}

extern "C" void kernel_launch(void* const* d_in, const int* in_sizes, int n_in,
                              void* d_out, int out_size, void* d_ws, size_t ws_size,
                              hipStream_t stream) {
  const float* s       = (const float*)d_in[0];
  const float* eps     = (const float*)d_in[1];
  const float* Wih_f   = (const float*)d_in[2];
  const float* Whh_f   = (const float*)d_in[3];
  const float* bih_f   = (const float*)d_in[4];
  const float* bhh_f   = (const float*)d_in[5];
  const float* Wih_b   = (const float*)d_in[6];
  const float* bih_b   = (const float*)d_in[8];
  const float* bhh_b   = (const float*)d_in[9];
  const float* W_sigma = (const float*)d_in[10];
  const float* b_sigma = (const float*)d_in[11];
  const float* W_mu    = (const float*)d_in[12];
  const float* b_mu    = (const float*)d_in[13];
  const float* W_h0    = (const float*)d_in[14];
  const float* b_h0    = (const float*)d_in[15];
  const float* Wih_d   = (const float*)d_in[16];
  const float* Whh_d   = (const float*)d_in[17];
  const float* bih_d   = (const float*)d_in[18];
  const float* bhh_d   = (const float*)d_in[19];
  const float* W_dec   = (const float*)d_in[20];
  const float* b_dec   = (const float*)d_in[21];

  char* ws = (char*)d_ws;
  int* FLAGS  = (int*)(ws + OFF_FLAGS);
  u64* HENCW  = (u64*)(ws + OFF_HENCW);
  u64* HDECW  = (u64*)(ws + OFF_HDECW);
  u16* WENCP  = (u16*)(ws + OFF_WENC);
  u16* WDECP  = (u16*)(ws + OFF_WDEC);
  u16* WYP    = (u16*)(ws + OFF_WY);
  u16* WMSP   = (u16*)(ws + OFF_WMS);
  u16* WH0P   = (u16*)(ws + OFF_WH0);
  u16* HLAT   = (u16*)(ws + OFF_HLAT);
  u16* AZ     = (u16*)(ws + OFF_AZ);
  u16* SXD    = (u16*)(ws + OFF_SX);
  float* out  = (float*)d_out;

  // zero latent flags + both tagged exchange buffers every launch (tag 0 = initial/invalid)
  hipMemsetAsync(ws, 0, (size_t)MEMSET_BYTES, stream);

  pack_wenc<<<1152, 256, 0, stream>>>(Whh_f, Wih_f, bih_f, bhh_f, WENCP);
  pack_wdec<<<5376, 256, 0, stream>>>(Whh_d, Wih_d, bih_d, bhh_d, WDECP);
  pack_wy<<<256, 256, 0, stream>>>(W_dec, WYP);
  pack_wms<<<544, 256, 0, stream>>>(W_mu, b_mu, W_sigma, b_sigma, WMSP);
  pack_wh0<<<320, 256, 0, stream>>>(W_h0, b_h0, WH0P);
  pack_sx<<<4096, 256, 0, stream>>>(s, SXD);

  rnn_persist<<<256, 256, 0, stream>>>(FLAGS, HENCW, HDECW, WENCP, WDECP, WYP, WMSP, WH0P,
                                       HLAT, AZ, SXD, s, eps,
                                       Wih_b, bih_b, bhh_b, b_dec, out);

  mdn_final<<<2048, 64, 0, stream>>>(out);

  (void)in_sizes; (void)n_in; (void)out_size; (void)ws_size;
}